// Round 1
// baseline (138.665 us; speedup 1.0000x reference)
//
#include <hip/hip_runtime.h>
#include <stdint.h>

#define NROWS 4000
#define NCOLS 30000
#define NC4   7500          // NCOLS / 4
#define BATCH 8
#define SPANS 500           // LEN_S * LEN_E
#define LEN_E_ 10
#define KLOG2E 14.4269504088896340736f   // (1/T) * log2(e), T = 0.1

// ---- detect element size of the 'viable' bool array (1 / 4 / 8 bytes) ----
// Counts nonzero bytes in the first 2048 bytes (buffer is >= 4000 bytes in
// every plausible encoding). Expected counts: u8 ~1024, f32 ~512, i32 ~256,
// i64 ~128 -> thresholds 800 / 192 separate by >10 sigma.
__device__ __forceinline__ int detect_elem_bytes(const uint8_t* __restrict__ p,
                                                 int tid) {
    __shared__ int s_count;
    if (tid == 0) s_count = 0;
    __syncthreads();
    int c = 0;
#pragma unroll
    for (int k = 0; k < 8; ++k) c += (p[tid * 8 + k] != 0);
#pragma unroll
    for (int off = 32; off > 0; off >>= 1) c += __shfl_down(c, off);
    if ((tid & 63) == 0) atomicAdd(&s_count, c);
    __syncthreads();
    int cnt = s_count;
    return cnt >= 800 ? 1 : (cnt >= 192 ? 4 : 8);
}

__device__ __forceinline__ bool viable_at(const void* __restrict__ p, int esz,
                                          int i) {
    if (esz == 1) return ((const uint8_t*)p)[i] != 0;
    if (esz == 4) return ((const uint32_t*)p)[i] != 0u;
    return ((const unsigned long long*)p)[i] != 0ull;
}

// ---- kernel 1: per-row online soft-min + argmin + threshold + mask ----
// out[32 + row] = viable ? (celu(1 - 40*softmin) + 1)/2 : 0
__global__ __launch_bounds__(256) void softmin_rows(
    const float* __restrict__ ed, const void* __restrict__ viable,
    float* __restrict__ out) {
    const int row = blockIdx.x;
    const int tid = threadIdx.x;

    const int esz = detect_elem_bytes((const uint8_t*)viable, tid);

    const float4* __restrict__ rp =
        (const float4*)(ed + (size_t)row * NCOLS);   // 120000 B/row, 16B aligned

    float m = INFINITY;   // running min (softmax reference point)
    int   mi = 0;         // argmin (first occurrence)
    float Z = 0.f, S = 0.f;

    for (int j = tid; j < NC4; j += 256) {
        float4 v = rp[j];
        const int base = j * 4;
#pragma unroll
        for (int c = 0; c < 4; ++c) {
            float x = (&v.x)[c];
            if (x < m) {                       // strict < keeps first occurrence
                float f = exp2f((x - m) * KLOG2E);   // rescale old partials
                Z *= f; S *= f;
                m = x; mi = base + c;
            }
            float e = exp2f((m - x) * KLOG2E); // <= 1, underflow to 0 is fine
            Z += e;
            S = fmaf(x, e, S);
        }
    }

    __shared__ float sm[256], sZ[256], sS[256];
    __shared__ int   si[256];
    sm[tid] = m; sZ[tid] = Z; sS[tid] = S; si[tid] = mi;
    __syncthreads();
    for (int off = 128; off > 0; off >>= 1) {
        if (tid < off) {
            float m1 = sm[tid],     Z1 = sZ[tid],     S1 = sS[tid];
            float m2 = sm[tid+off], Z2 = sZ[tid+off], S2 = sS[tid+off];
            int   i1 = si[tid],     i2 = si[tid+off];
            float ml = fminf(m1, m2);
            float f1 = exp2f((ml - m1) * KLOG2E);
            float f2 = exp2f((ml - m2) * KLOG2E);
            sZ[tid] = Z1 * f1 + Z2 * f2;
            sS[tid] = S1 * f1 + S2 * f2;
            sm[tid] = ml;
            // prefer strictly smaller value; on equal value, smaller index
            si[tid] = (m2 < m1 || (m2 == m1 && i2 < i1)) ? i2 : i1;
        }
        __syncthreads();
    }

    if (tid == 0) {
        float ed_v  = sS[0] / sZ[0];           // soft-min value
        float z     = 1.f - 40.f * ed_v;       // 1 - 2x/thresh, thresh=0.05
        float celu  = z > 0.f ? z : expm1f(z);
        float score = 0.5f * (celu + 1.f);
        out[32 + row] = viable_at(viable, esz, row) ? score : 0.f;
    }
}

// ---- kernel 2: per-batch soft-max over 500 span scores + outputs ----
__global__ __launch_bounds__(256) void span_softmax(
    const float* __restrict__ ed, float* __restrict__ out) {
    const int b   = blockIdx.x;
    const int tid = threadIdx.x;
    const float* __restrict__ sc = out + 32 + b * SPANS;

    __shared__ float sv[256];
    __shared__ int   si[256];

    // phase 1: max + argmax (first occurrence)
    float mx = -INFINITY; int ai = 0;
    for (int j = tid; j < SPANS; j += 256) {
        float x = sc[j];
        if (x > mx) { mx = x; ai = j; }
    }
    sv[tid] = mx; si[tid] = ai;
    __syncthreads();
    for (int off = 128; off > 0; off >>= 1) {
        if (tid < off) {
            float v2 = sv[tid+off]; int i2 = si[tid+off];
            if (v2 > sv[tid] || (v2 == sv[tid] && i2 < si[tid])) {
                sv[tid] = v2; si[tid] = i2;
            }
        }
        __syncthreads();
    }
    const float M    = sv[0];
    const int   best = si[0];
    __syncthreads();

    // phase 2: softmax-weighted sum
    float Z = 0.f, S = 0.f;
    for (int j = tid; j < SPANS; j += 256) {
        float x = sc[j];
        float e = exp2f((x - M) * KLOG2E);
        Z += e;
        S = fmaf(x, e, S);
    }
    __shared__ float sZ[256], sS[256];
    sZ[tid] = Z; sS[tid] = S;
    __syncthreads();
    for (int off = 128; off > 0; off >>= 1) {
        if (tid < off) { sZ[tid] += sZ[tid+off]; sS[tid] += sS[tid+off]; }
        __syncthreads();
    }
    const float best_score = sS[0] / sZ[0];
    __syncthreads();

    // phase 3: recompute argmin (vocab index) over the winning row only
    const float* __restrict__ rp =
        ed + ((size_t)b * SPANS + (size_t)best) * NCOLS;
    float mv = INFINITY; int vi = 0;
    for (int j = tid; j < NCOLS; j += 256) {
        float x = rp[j];
        if (x < mv) { mv = x; vi = j; }
    }
    sv[tid] = mv; si[tid] = vi;
    __syncthreads();
    for (int off = 128; off > 0; off >>= 1) {
        if (tid < off) {
            float v2 = sv[tid+off]; int i2 = si[tid+off];
            if (v2 < sv[tid] || (v2 == sv[tid] && i2 < si[tid])) {
                sv[tid] = v2; si[tid] = i2;
            }
        }
        __syncthreads();
    }

    if (tid == 0) {
        int start = best / LEN_E_;
        int len   = best % LEN_E_;
        out[b]          = best_score;
        out[8 + b]      = (float)start;
        out[16 + b]     = (float)(start + len);
        // selected span viable iff its score > 0 (thresholded scores are
        // strictly positive; non-viable slots are exactly 0)
        out[24 + b]     = (M > 0.f) ? (float)si[0] : -1.f;
    }
}

extern "C" void kernel_launch(void* const* d_in, const int* in_sizes, int n_in,
                              void* d_out, int out_size, void* d_ws,
                              size_t ws_size, hipStream_t stream) {
    const float* ed     = (const float*)d_in[0];
    const void*  viable = d_in[4];   // ed_dist, bi, lsi, lei, viable
    float* out = (float*)d_out;

    hipLaunchKernelGGL(softmin_rows, dim3(NROWS), dim3(256), 0, stream,
                       ed, viable, out);
    hipLaunchKernelGGL(span_softmax, dim3(BATCH), dim3(256), 0, stream,
                       ed, out);
}

// Round 2
// 106.195 us; speedup vs baseline: 1.3058x; 1.3058x over previous
//
#include <hip/hip_runtime.h>
#include <stdint.h>

#define NROWS 4000
#define NCOLS 30000
#define NC8   3750          // NCOLS / 8 (two float4 per iter)
#define BATCH 8
#define SPANS 500           // LEN_S * LEN_E
#define LEN_E_ 10
#define KLOG2E 14.4269504088896340736f   // (1/T) * log2(e), T = 0.1

__device__ __forceinline__ float fexp2(float x) {
    return __builtin_amdgcn_exp2f(x);    // raw v_exp_f32; underflow->0 is fine
}

// ---- detect element size of the 'viable' bool array (1 / 4 / 8 bytes) ----
// Counts nonzero bytes in the first 2048 bytes. Expected nonzero-byte counts:
// u8 ~1024, f32 ~512, i32 ~256, i64 ~128 -> thresholds 800 / 192.
__device__ __forceinline__ int detect_elem_bytes(const uint8_t* __restrict__ p,
                                                 int tid) {
    __shared__ int s_count;
    if (tid == 0) s_count = 0;
    __syncthreads();
    int c = 0;
#pragma unroll
    for (int k = 0; k < 8; ++k) c += (p[tid * 8 + k] != 0);
#pragma unroll
    for (int off = 32; off > 0; off >>= 1) c += __shfl_down(c, off);
    if ((tid & 63) == 0) atomicAdd(&s_count, c);
    __syncthreads();
    int cnt = s_count;
    return cnt >= 800 ? 1 : (cnt >= 192 ? 4 : 8);
}

__device__ __forceinline__ bool viable_at(const void* __restrict__ p, int esz,
                                          int i) {
    if (esz == 1) return ((const uint8_t*)p)[i] != 0;
    if (esz == 4) return ((const uint32_t*)p)[i] != 0u;
    return ((const unsigned long long*)p)[i] != 0ull;
}

// ---- kernel 1: per-row soft-min (fixed reference m=0) + threshold + mask ----
// ed >= 0, so e = exp2(-x*K) <= 1: no overflow, no rescale, no branch.
// out[32 + row] = viable ? (celu(1 - 40*softmin) + 1)/2 : 0
__global__ __launch_bounds__(256) void softmin_rows(
    const float* __restrict__ ed, const void* __restrict__ viable,
    float* __restrict__ out) {
    const int row = blockIdx.x;
    const int tid = threadIdx.x;

    const int esz = detect_elem_bytes((const uint8_t*)viable, tid);

    const float4* __restrict__ rp =
        (const float4*)(ed + (size_t)row * NCOLS);   // 120000 B, 16B aligned

    float Z = 0.f, S = 0.f;
    for (int j = tid; j < NC8; j += 256) {
        float4 a = rp[2 * j];
        float4 b = rp[2 * j + 1];
#pragma unroll
        for (int c = 0; c < 4; ++c) {
            float x = (&a.x)[c];
            float e = fexp2(x * -KLOG2E);
            Z += e;
            S = fmaf(x, e, S);
        }
#pragma unroll
        for (int c = 0; c < 4; ++c) {
            float x = (&b.x)[c];
            float e = fexp2(x * -KLOG2E);
            Z += e;
            S = fmaf(x, e, S);
        }
    }

    // wave shuffle reduce, then cross-wave via LDS
#pragma unroll
    for (int off = 32; off > 0; off >>= 1) {
        Z += __shfl_down(Z, off);
        S += __shfl_down(S, off);
    }
    __shared__ float wZ[4], wS[4];
    if ((tid & 63) == 0) { wZ[tid >> 6] = Z; wS[tid >> 6] = S; }
    __syncthreads();

    if (tid == 0) {
        float Zt = (wZ[0] + wZ[1]) + (wZ[2] + wZ[3]);
        float St = (wS[0] + wS[1]) + (wS[2] + wS[3]);
        float ed_v  = St / Zt;                 // soft-min value
        float z     = 1.f - 40.f * ed_v;       // 1 - 2x/thresh, thresh=0.05
        float celu  = z > 0.f ? z : expm1f(z);
        float score = 0.5f * (celu + 1.f);
        out[32 + row] = viable_at(viable, esz, row) ? score : 0.f;
    }
}

// ---- kernel 2: per-batch soft-max over 500 span scores + outputs ----
__global__ __launch_bounds__(256) void span_softmax(
    const float* __restrict__ ed, float* __restrict__ out) {
    const int b   = blockIdx.x;
    const int tid = threadIdx.x;
    const float* __restrict__ sc = out + 32 + b * SPANS;

    __shared__ float sv[256];
    __shared__ int   si[256];

    // phase 1: max + argmax (first occurrence)
    float mx = -INFINITY; int ai = 0;
    for (int j = tid; j < SPANS; j += 256) {
        float x = sc[j];
        if (x > mx) { mx = x; ai = j; }
    }
    sv[tid] = mx; si[tid] = ai;
    __syncthreads();
    for (int off = 128; off > 0; off >>= 1) {
        if (tid < off) {
            float v2 = sv[tid+off]; int i2 = si[tid+off];
            if (v2 > sv[tid] || (v2 == sv[tid] && i2 < si[tid])) {
                sv[tid] = v2; si[tid] = i2;
            }
        }
        __syncthreads();
    }
    const float M    = sv[0];
    const int   best = si[0];
    __syncthreads();

    // phase 2: softmax-weighted sum over the 500 spans
    float Z = 0.f, S = 0.f;
    for (int j = tid; j < SPANS; j += 256) {
        float x = sc[j];
        float e = fexp2((x - M) * KLOG2E);
        Z += e;
        S = fmaf(x, e, S);
    }
    __shared__ float sZ[256], sS[256];
    sZ[tid] = Z; sS[tid] = S;
    __syncthreads();
    for (int off = 128; off > 0; off >>= 1) {
        if (tid < off) { sZ[tid] += sZ[tid+off]; sS[tid] += sS[tid+off]; }
        __syncthreads();
    }
    const float best_score = sS[0] / sZ[0];
    __syncthreads();

    // phase 3: argmin (vocab index) over the winning row only, float4 loads
    const float4* __restrict__ rp = (const float4*)(
        ed + ((size_t)b * SPANS + (size_t)best) * NCOLS);
    float mv = INFINITY; int vi = 0;
    for (int j = tid; j < NCOLS / 4; j += 256) {
        float4 v = rp[j];
        const int base = j * 4;
#pragma unroll
        for (int c = 0; c < 4; ++c) {
            float x = (&v.x)[c];
            if (x < mv) { mv = x; vi = base + c; }   // strict <: first occurrence
        }
    }
    sv[tid] = mv; si[tid] = vi;
    __syncthreads();
    for (int off = 128; off > 0; off >>= 1) {
        if (tid < off) {
            float v2 = sv[tid+off]; int i2 = si[tid+off];
            if (v2 < sv[tid] || (v2 == sv[tid] && i2 < si[tid])) {
                sv[tid] = v2; si[tid] = i2;
            }
        }
        __syncthreads();
    }

    if (tid == 0) {
        int start = best / LEN_E_;
        int len   = best % LEN_E_;
        out[b]          = best_score;
        out[8 + b]      = (float)start;
        out[16 + b]     = (float)(start + len);
        // viable slots have strictly positive scores; non-viable are exactly 0
        out[24 + b]     = (M > 0.f) ? (float)si[0] : -1.f;
    }
}

extern "C" void kernel_launch(void* const* d_in, const int* in_sizes, int n_in,
                              void* d_out, int out_size, void* d_ws,
                              size_t ws_size, hipStream_t stream) {
    const float* ed     = (const float*)d_in[0];
    const void*  viable = d_in[4];   // ed_dist, bi, lsi, lei, viable
    float* out = (float*)d_out;

    hipLaunchKernelGGL(softmin_rows, dim3(NROWS), dim3(256), 0, stream,
                       ed, viable, out);
    hipLaunchKernelGGL(span_softmax, dim3(BATCH), dim3(256), 0, stream,
                       ed, out);
}

// Round 3
// 91.430 us; speedup vs baseline: 1.5166x; 1.1615x over previous
//
#include <hip/hip_runtime.h>
#include <stdint.h>

#define NROWS 4000
#define NCOLS 30000
#define NQ4   1875          // NCOLS / 16 (four float4 per thread-iter)
#define BATCH 8
#define SPANS 500           // LEN_S * LEN_E
#define LEN_E_ 10
#define KLOG2E 14.4269504088896340736f   // (1/T) * log2(e), T = 0.1

__device__ __forceinline__ float fexp2(float x) {
    return __builtin_amdgcn_exp2f(x);    // raw v_exp_f32; underflow->0 is fine
}

// ---- detect element size of the 'viable' bool array (1 / 4 / 8 bytes) ----
// Counts nonzero bytes in the first 2048 bytes. Expected nonzero-byte counts:
// u8 ~1024, f32 ~512, i32 ~256, i64 ~128 -> thresholds 800 / 192.
__device__ __forceinline__ int detect_elem_bytes(const uint8_t* __restrict__ p,
                                                 int tid) {
    __shared__ int s_count;
    if (tid == 0) s_count = 0;
    __syncthreads();
    int c = 0;
#pragma unroll
    for (int k = 0; k < 8; ++k) c += (p[tid * 8 + k] != 0);
#pragma unroll
    for (int off = 32; off > 0; off >>= 1) c += __shfl_down(c, off);
    if ((tid & 63) == 0) atomicAdd(&s_count, c);
    __syncthreads();
    int cnt = s_count;
    return cnt >= 800 ? 1 : (cnt >= 192 ? 4 : 8);
}

__device__ __forceinline__ bool viable_at(const void* __restrict__ p, int esz,
                                          int i) {
    if (esz == 1) return ((const uint8_t*)p)[i] != 0;
    if (esz == 4) return ((const uint32_t*)p)[i] != 0u;
    return ((const unsigned long long*)p)[i] != 0ull;
}

// ---- kernel 1: per-row soft-min (fixed ref m=0) + argmin + threshold ------
// ed >= 0, so e = exp2(-x*K) <= 1: no overflow, no rescale, no branch.
// Per-thread element order is monotonic in index (16 consecutive elems/iter),
// so strict < tracking + lexicographic (value,index) reduce = jnp.argmin
// first-occurrence semantics exactly.
__global__ __launch_bounds__(256) void softmin_rows(
    const float* __restrict__ ed, const void* __restrict__ viable,
    float* __restrict__ out, int* __restrict__ amin) {
    const int row = blockIdx.x;
    const int tid = threadIdx.x;

    const int esz = detect_elem_bytes((const uint8_t*)viable, tid);

    const float4* __restrict__ rp =
        (const float4*)(ed + (size_t)row * NCOLS);   // 120000 B, 16B aligned

    float Z = 0.f, S = 0.f, mv = INFINITY;
    int   vi = 0;

    for (int j = tid; j < NQ4; j += 256) {
        float4 vv[4];
        vv[0] = rp[4 * j + 0];
        vv[1] = rp[4 * j + 1];
        vv[2] = rp[4 * j + 2];
        vv[3] = rp[4 * j + 3];
        const int base = j << 4;
#pragma unroll
        for (int q = 0; q < 4; ++q) {
#pragma unroll
            for (int c = 0; c < 4; ++c) {
                float x = (&vv[q].x)[c];
                float e = fexp2(x * -KLOG2E);
                Z += e;
                S = fmaf(x, e, S);
                bool lt = x < mv;              // cndmask pair, no branch
                mv = lt ? x : mv;
                vi = lt ? (base + q * 4 + c) : vi;
            }
        }
    }

    // wave shuffle reduce (sum Z,S; lexicographic min (mv,vi))
#pragma unroll
    for (int off = 32; off > 0; off >>= 1) {
        Z += __shfl_down(Z, off);
        S += __shfl_down(S, off);
        float ov = __shfl_down(mv, off);
        int   oi = __shfl_down(vi, off);
        if (ov < mv || (ov == mv && oi < vi)) { mv = ov; vi = oi; }
    }
    __shared__ float wZ[4], wS[4], wM[4];
    __shared__ int   wI[4];
    if ((tid & 63) == 0) {
        int w = tid >> 6;
        wZ[w] = Z; wS[w] = S; wM[w] = mv; wI[w] = vi;
    }
    __syncthreads();

    if (tid == 0) {
        float Zt = 0.f, St = 0.f, m = INFINITY;
        int ii = 0;
#pragma unroll
        for (int w = 0; w < 4; ++w) {
            Zt += wZ[w]; St += wS[w];
            if (wM[w] < m || (wM[w] == m && wI[w] < ii)) { m = wM[w]; ii = wI[w]; }
        }
        float ed_v  = St / Zt;                 // soft-min value
        float z     = 1.f - 40.f * ed_v;       // 1 - 2x/thresh, thresh=0.05
        float celu  = z > 0.f ? z : expm1f(z);
        float score = 0.5f * (celu + 1.f);
        amin[row]     = ii;
        out[32 + row] = viable_at(viable, esz, row) ? score : 0.f;
    }
}

// ---- kernel 2: per-batch soft-max over 500 span scores + outputs ----------
__global__ __launch_bounds__(256) void span_softmax(
    const int* __restrict__ amin, float* __restrict__ out) {
    const int b   = blockIdx.x;
    const int tid = threadIdx.x;
    const float* __restrict__ sc = out + 32 + b * SPANS;

    __shared__ float sv[256];
    __shared__ int   si[256];

    // phase 1: max + argmax (first occurrence)
    float mx = -INFINITY; int ai = 0;
    for (int j = tid; j < SPANS; j += 256) {
        float x = sc[j];
        if (x > mx) { mx = x; ai = j; }
    }
    sv[tid] = mx; si[tid] = ai;
    __syncthreads();
    for (int off = 128; off > 0; off >>= 1) {
        if (tid < off) {
            float v2 = sv[tid+off]; int i2 = si[tid+off];
            if (v2 > sv[tid] || (v2 == sv[tid] && i2 < si[tid])) {
                sv[tid] = v2; si[tid] = i2;
            }
        }
        __syncthreads();
    }
    const float M    = sv[0];
    const int   best = si[0];
    __syncthreads();

    // phase 2: softmax-weighted sum over the 500 spans
    float Z = 0.f, S = 0.f;
    for (int j = tid; j < SPANS; j += 256) {
        float x = sc[j];
        float e = fexp2((x - M) * KLOG2E);
        Z += e;
        S = fmaf(x, e, S);
    }
    __shared__ float sZ[256], sS[256];
    sZ[tid] = Z; sS[tid] = S;
    __syncthreads();
    for (int off = 128; off > 0; off >>= 1) {
        if (tid < off) { sZ[tid] += sZ[tid+off]; sS[tid] += sS[tid+off]; }
        __syncthreads();
    }

    if (tid == 0) {
        int start = best / LEN_E_;
        int len   = best % LEN_E_;
        out[b]      = sS[0] / sZ[0];
        out[8 + b]  = (float)start;
        out[16 + b] = (float)(start + len);
        // viable slots have strictly positive scores; non-viable are exactly 0
        out[24 + b] = (M > 0.f) ? (float)amin[b * SPANS + best] : -1.f;
    }
}

extern "C" void kernel_launch(void* const* d_in, const int* in_sizes, int n_in,
                              void* d_out, int out_size, void* d_ws,
                              size_t ws_size, hipStream_t stream) {
    const float* ed     = (const float*)d_in[0];
    const void*  viable = d_in[4];   // ed_dist, bi, lsi, lei, viable
    float* out  = (float*)d_out;
    int*   amin = (int*)d_ws;        // 4000 ints = 16 KB scratch

    hipLaunchKernelGGL(softmin_rows, dim3(NROWS), dim3(256), 0, stream,
                       ed, viable, out, amin);
    hipLaunchKernelGGL(span_softmax, dim3(BATCH), dim3(256), 0, stream,
                       amin, out);
}